// Round 10
// baseline (323.788 us; speedup 1.0000x reference)
//
#include <hip/hip_runtime.h>
#include <hip/hip_bf16.h>

#define SEQ 2048
#define HD 128
#define NH 32
#define NKV 8
#define ODIM 4096
#define QB 64
#define KVB 64
#define SCALE 0.08838834764831845f
#define NEGBIG -1e9f

typedef __attribute__((ext_vector_type(8))) short bf16x8;
typedef __attribute__((ext_vector_type(4))) float f32x4;

__device__ __forceinline__ unsigned short f2bf(float x) {
  union { __hip_bfloat16 b; unsigned short u; } c;
  c.b = __float2bfloat16(x);  // RNE, single HW cvt
  return c.u;
}

__device__ __forceinline__ unsigned pack2bf(float lo, float hi) {
  union { __hip_bfloat162 h; unsigned u; } c;
  c.h = __float22bfloat162_rn(float2{lo, hi});  // x=lo (low 16b), y=hi
  return c.u;
}

// Q-tile-pair fusion: block = 256 threads (4 waves), one head, Q-tiles
// {p, 31-p}. Each wave owns strip w of BOTH tiles -> every K/V^T LDS
// fragment read feeds 2 MFMAs (tiles share the head's K/V), every wave
// carries exactly 33 tile-units (perfect balance, no idle waves), and the
// grid stays 512 blocks (~3 blocks/CU with launch_bounds(256,3)).
// Swapped-operand MFMA: S^T = mfma(K, Q), O^T = mfma(V, P); lane owns one
// P-row per tile; softmax stats scalar; P stays in registers.
__global__ __launch_bounds__(256, 3) void sdpa_flash_kernel(
    const float* __restrict__ q, const float* __restrict__ k,
    const float* __restrict__ v, float* __restrict__ out) {
  // LDS: K [64][128] bf16 swz (16KB) + V^T [128][64] bf16 swz (16KB)
  __shared__ __align__(16) unsigned char smem[32768];
  unsigned char* Klds = smem;
  unsigned char* Vlds = smem + 16384;
  const int tid = threadIdx.x;
  const int w = tid >> 6;              // 0..3: strip index in both tiles
  const int l = tid & 63;
  const int lm = l & 15;
  const int lg = l >> 4;

  const int p = (int)blockIdx.x;       // 0..15 -> Q-tile pair {p, 31-p}
  const int qtA = p;
  const int qtB = 31 - p;
  const int h = (int)blockIdx.y;
  const int hkv = h >> 2;              // repeat_interleave: kv head = h / 4
  const int rowA = qtA * QB + 16 * w + lm;
  const int rowB = qtB * QB + 16 * w + lm;

  // ---- Q fragments for both tiles, pre-scaled by 1/sqrt(D) ----
  // lane holds Q[q = row][d = 32*c + 8*lg + j], j=0..7 contiguous
  bf16x8 qa0[4], qa1[4];
  {
    const int rows[2] = {rowA, rowB};
    #pragma unroll
    for (int u = 0; u < 2; ++u) {
      const float* qr = q + ((size_t)(h * SEQ + rows[u])) * HD + 8 * lg;
      #pragma unroll
      for (int c = 0; c < 4; ++c) {
        float4 a = *(const float4*)(qr + 32 * c);
        float4 b = *(const float4*)(qr + 32 * c + 4);
        union { unsigned short hh[8]; bf16x8 vv; } pk;
        pk.hh[0] = f2bf(a.x * SCALE); pk.hh[1] = f2bf(a.y * SCALE);
        pk.hh[2] = f2bf(a.z * SCALE); pk.hh[3] = f2bf(a.w * SCALE);
        pk.hh[4] = f2bf(b.x * SCALE); pk.hh[5] = f2bf(b.y * SCALE);
        pk.hh[6] = f2bf(b.z * SCALE); pk.hh[7] = f2bf(b.w * SCALE);
        if (u == 0) qa0[c] = pk.vv; else qa1[c] = pk.vv;
      }
    }
  }

  // O^T accumulators: o[nt2][i] = O[q=row][d = 16*nt2 + 4*lg + i]
  f32x4 o0[8], o1[8];
  #pragma unroll
  for (int i = 0; i < 8; ++i) {
    o0[i] = (f32x4){0.f, 0.f, 0.f, 0.f};
    o1[i] = (f32x4){0.f, 0.f, 0.f, 0.f};
  }
  float m0 = -1e30f, m1 = -1e30f;
  float l0 = 0.f, l1 = 0.f;

  const int ntiles = qtB + 1;
  const float* kg0 = k + (size_t)hkv * SEQ * HD;
  const float* vg0 = v + (size_t)hkv * SEQ * HD;

  // softmax + in-register P-fragment build (per tile-unit)
  auto sm_update = [&](f32x4 (&s)[4], float& m, float& lr, f32x4 (&oo)[8],
                       bf16x8 (&pb)[2]) {
    float tm = -1e30f;
    #pragma unroll
    for (int nt = 0; nt < 4; ++nt)
      #pragma unroll
      for (int i = 0; i < 4; ++i) tm = fmaxf(tm, s[nt][i]);
    tm = fmaxf(tm, __shfl_xor(tm, 16));
    tm = fmaxf(tm, __shfl_xor(tm, 32));
    float mn = fmaxf(m, tm);
    float fac = __expf(m - mn);
    m = mn;
    float rs = 0.f;
    #pragma unroll
    for (int nt = 0; nt < 4; ++nt) {
      #pragma unroll
      for (int i = 0; i < 4; ++i) {
        float pv = __expf(s[nt][i] - mn);
        s[nt][i] = pv;
        rs += pv;
      }
    }
    rs += __shfl_xor(rs, 16);
    rs += __shfl_xor(rs, 32);
    lr = lr * fac + rs;
    #pragma unroll
    for (int nt2 = 0; nt2 < 8; ++nt2)
      #pragma unroll
      for (int i = 0; i < 4; ++i) oo[nt2][i] *= fac;

    // lane needs P[q=lm][kv = 32*kc + 8*lg + j], j=0..7
    unsigned pk0[4], pk1[4];
    #pragma unroll
    for (int nt = 0; nt < 4; ++nt) {
      pk0[nt] = pack2bf(s[nt][0], s[nt][1]);
      pk1[nt] = pack2bf(s[nt][2], s[nt][3]);
    }
    const int srcA = lm + ((lg & 1) << 5);
    const int srcB = srcA + 16;
    const bool lo2 = (lg < 2);
    #pragma unroll
    for (int kc = 0; kc < 2; ++kc) {
      int a0 = __shfl((int)pk0[2*kc], srcA), b0 = __shfl((int)pk0[2*kc+1], srcA);
      int a1 = __shfl((int)pk1[2*kc], srcA), b1 = __shfl((int)pk1[2*kc+1], srcA);
      int a2 = __shfl((int)pk0[2*kc], srcB), b2 = __shfl((int)pk0[2*kc+1], srcB);
      int a3 = __shfl((int)pk1[2*kc], srcB), b3 = __shfl((int)pk1[2*kc+1], srcB);
      union { int uu[4]; bf16x8 v; } pw;
      pw.uu[0] = lo2 ? a0 : b0;  // kv 8lg+{0,1}
      pw.uu[1] = lo2 ? a1 : b1;  // kv 8lg+{2,3}
      pw.uu[2] = lo2 ? a2 : b2;  // kv 8lg+{4,5}
      pw.uu[3] = lo2 ? a3 : b3;  // kv 8lg+{6,7}
      pb[kc] = pw.v;
    }
  };

  auto apply_mask = [&](f32x4 (&s)[4], int row, int kv0) {
    #pragma unroll
    for (int nt = 0; nt < 4; ++nt) {
      #pragma unroll
      for (int i = 0; i < 4; ++i) {
        int col = kv0 + (nt << 4) + (lg << 2) + i;
        s[nt][i] += (col > row) ? NEGBIG : 0.f;
      }
    }
  };

  for (int t = 0; t < ntiles; ++t) {
    const int kv0 = t * KVB;
    __syncthreads();  // previous tile's LDS reads complete

    // ---- stage K tile: [kv][d] bf16, b128 writes, XOR-swizzled ----
    {
      const float* kg = kg0 + (size_t)kv0 * HD;
      #pragma unroll
      for (int it = 0; it < 4; ++it) {
        int idx = it * 256 + tid;   // 0..1023
        int r = idx >> 4;           // kv row 0..63
        int c8 = (idx & 15) << 3;   // d start
        const float* src = kg + r * HD + c8;
        float4 a = *(const float4*)(src);
        float4 b = *(const float4*)(src + 4);
        union { unsigned short hh[8]; uint4 u4; } pk;
        pk.hh[0]=f2bf(a.x); pk.hh[1]=f2bf(a.y); pk.hh[2]=f2bf(a.z); pk.hh[3]=f2bf(a.w);
        pk.hh[4]=f2bf(b.x); pk.hh[5]=f2bf(b.y); pk.hh[6]=f2bf(b.z); pk.hh[7]=f2bf(b.w);
        int byte = (r << 8) + ((c8 << 1) ^ ((r & 7) << 4));
        *(uint4*)(Klds + byte) = pk.u4;
      }
      // ---- stage V^T: [d][kv] bf16, packed kv-pair b32 writes ----
      const float* vg = vg0 + (size_t)kv0 * HD;
      #pragma unroll
      for (int it = 0; it < 2; ++it) {
        int idx = it * 256 + tid;    // 0..511
        int rr = (idx & 31) << 1;    // even kv row
        int db = idx >> 5;           // d-block 0..15
        const float* s0 = vg + rr * HD + (db << 3);
        const float* s1 = s0 + HD;
        float4 a0 = *(const float4*)(s0);
        float4 b0 = *(const float4*)(s0 + 4);
        float4 a1 = *(const float4*)(s1);
        float4 b1 = *(const float4*)(s1 + 4);
        float lo[8] = {a0.x,a0.y,a0.z,a0.w,b0.x,b0.y,b0.z,b0.w};
        float hi[8] = {a1.x,a1.y,a1.z,a1.w,b1.x,b1.y,b1.z,b1.w};
        #pragma unroll
        for (int j = 0; j < 8; ++j) {
          int d = (db << 3) + j;
          int byte = (d << 7) + ((rr << 1) ^ ((d & 7) << 4));
          *(unsigned*)(Vlds + byte) = pack2bf(lo[j], hi[j]);
        }
      }
    }
    __syncthreads();

    const bool doA = (t <= qtA);  // tile A active; tile B active every t

    // ---- S^T = K Q^T: one kb read feeds both tiles' MFMAs ----
    f32x4 s0[4], s1[4];
    #pragma unroll
    for (int nt = 0; nt < 4; ++nt) {
      s0[nt] = (f32x4){0.f, 0.f, 0.f, 0.f};
      s1[nt] = (f32x4){0.f, 0.f, 0.f, 0.f};
    }
    if (doA) {
      #pragma unroll
      for (int nt = 0; nt < 4; ++nt) {
        int r = (nt << 4) + lm;
        #pragma unroll
        for (int kc = 0; kc < 4; ++kc) {
          int byte = (r << 8) + (((kc << 6) + (lg << 4)) ^ ((r & 7) << 4));
          bf16x8 kb = *(const bf16x8*)(Klds + byte);
          s1[nt] = __builtin_amdgcn_mfma_f32_16x16x32_bf16(kb, qa1[kc], s1[nt], 0, 0, 0);
          s0[nt] = __builtin_amdgcn_mfma_f32_16x16x32_bf16(kb, qa0[kc], s0[nt], 0, 0, 0);
        }
      }
    } else {
      #pragma unroll
      for (int nt = 0; nt < 4; ++nt) {
        int r = (nt << 4) + lm;
        #pragma unroll
        for (int kc = 0; kc < 4; ++kc) {
          int byte = (r << 8) + (((kc << 6) + (lg << 4)) ^ ((r & 7) << 4));
          bf16x8 kb = *(const bf16x8*)(Klds + byte);
          s1[nt] = __builtin_amdgcn_mfma_f32_16x16x32_bf16(kb, qa1[kc], s1[nt], 0, 0, 0);
        }
      }
    }

    // ---- causal mask: only the diagonal tile of each needs it ----
    if (t == qtB) apply_mask(s1, rowB, kv0);
    if (doA && t == qtA) apply_mask(s0, rowA, kv0);

    // ---- online softmax + in-register P, per active tile ----
    bf16x8 pb0[2], pb1[2];
    sm_update(s1, m1, l1, o1, pb1);
    if (doA) sm_update(s0, m0, l0, o0, pb0);

    // ---- O^T += V^T P^T: one vb read feeds both tiles' MFMAs ----
    if (doA) {
      #pragma unroll
      for (int nt2 = 0; nt2 < 8; ++nt2) {
        int dr = (nt2 << 4) + lm;
        #pragma unroll
        for (int kc = 0; kc < 2; ++kc) {
          int byte = (dr << 7) + (((kc << 6) + (lg << 4)) ^ ((dr & 7) << 4));
          bf16x8 vb = *(const bf16x8*)(Vlds + byte);
          o1[nt2] = __builtin_amdgcn_mfma_f32_16x16x32_bf16(vb, pb1[kc], o1[nt2], 0, 0, 0);
          o0[nt2] = __builtin_amdgcn_mfma_f32_16x16x32_bf16(vb, pb0[kc], o0[nt2], 0, 0, 0);
        }
      }
    } else {
      #pragma unroll
      for (int nt2 = 0; nt2 < 8; ++nt2) {
        int dr = (nt2 << 4) + lm;
        #pragma unroll
        for (int kc = 0; kc < 2; ++kc) {
          int byte = (dr << 7) + (((kc << 6) + (lg << 4)) ^ ((dr & 7) << 4));
          bf16x8 vb = *(const bf16x8*)(Vlds + byte);
          o1[nt2] = __builtin_amdgcn_mfma_f32_16x16x32_bf16(vb, pb1[kc], o1[nt2], 0, 0, 0);
        }
      }
    }
  }

  // ---- epilogue: O /= l, coalesced float4 stores, both tiles ----
  {
    float inv = 1.f / l0;
    float* orow = out + (size_t)rowA * ODIM + h * HD + (lg << 2);
    #pragma unroll
    for (int nt2 = 0; nt2 < 8; ++nt2) {
      float4 st = {o0[nt2][0] * inv, o0[nt2][1] * inv,
                   o0[nt2][2] * inv, o0[nt2][3] * inv};
      *(float4*)(orow + (nt2 << 4)) = st;
    }
  }
  {
    float inv = 1.f / l1;
    float* orow = out + (size_t)rowB * ODIM + h * HD + (lg << 2);
    #pragma unroll
    for (int nt2 = 0; nt2 < 8; ++nt2) {
      float4 st = {o1[nt2][0] * inv, o1[nt2][1] * inv,
                   o1[nt2][2] * inv, o1[nt2][3] * inv};
      *(float4*)(orow + (nt2 << 4)) = st;
    }
  }
}

extern "C" void kernel_launch(void* const* d_in, const int* in_sizes, int n_in,
                              void* d_out, int out_size, void* d_ws, size_t ws_size,
                              hipStream_t stream) {
  // inputs: [0]=input_pos(i64) [1]=q(f32) [2]=k(f32) [3]=v(f32)
  //         [4]=bsz [5]=seqlen [6]=mask(f32, pure causal -> computed analytically)
  const float* q = (const float*)d_in[1];
  const float* k = (const float*)d_in[2];
  const float* v = (const float*)d_in[3];
  float* out = (float*)d_out;
  dim3 grid(SEQ / QB / 2, NH);  // 16 Q-tile pairs x 32 heads = 512 blocks
  sdpa_flash_kernel<<<grid, 256, 0, stream>>>(q, k, v, out);
}

// Round 11
// 169.116 us; speedup vs baseline: 1.9146x; 1.9146x over previous
//
#include <hip/hip_runtime.h>
#include <hip/hip_bf16.h>

#define SEQ 2048
#define HD 128
#define NH 32
#define NKV 8
#define ODIM 4096
#define QB 64
#define KVB 64
#define SCALE 0.08838834764831845f
#define NEGBIG -1e9f

typedef __attribute__((ext_vector_type(8))) short bf16x8;
typedef __attribute__((ext_vector_type(4))) float f32x4;

__device__ __forceinline__ unsigned short f2bf(float x) {
  union { __hip_bfloat16 b; unsigned short u; } c;
  c.b = __float2bfloat16(x);  // RNE, single HW cvt
  return c.u;
}

__device__ __forceinline__ unsigned pack2bf(float lo, float hi) {
  union { __hip_bfloat162 h; unsigned u; } c;
  c.h = __float22bfloat162_rn(float2{lo, hi});  // x=lo (low 16b), y=hi
  return c.u;
}

// Block = 256 threads (4 waves) x ONE Q-tile x head-pair (2hp, 2hp+1).
// Grid = 32 qt x 16 hp = 512 blocks (~2/CU). Each wave computes BOTH heads
// per K/V^T LDS fragment read (2 MFMAs per ds_read_b128) -> LDS-read pipe
// (r8's 60%-of-cycles consumer) halved, while keeping r8's 2-block/CU
// concurrency. Clean r9-style codegen: unrolled static-index u loops only.
// Swapped-operand MFMA: S^T = mfma(K, Q), O^T = mfma(V, P); lane owns one
// P-row per head; softmax stats scalar per head; P stays in registers.
__global__ __launch_bounds__(256, 2) void sdpa_flash_kernel(
    const float* __restrict__ q, const float* __restrict__ k,
    const float* __restrict__ v, float* __restrict__ out) {
  // LDS: K [64][128] bf16 swz (16KB) + V^T [128][64] bf16 swz (16KB)
  __shared__ __align__(16) unsigned char smem[32768];
  unsigned char* Klds = smem;
  unsigned char* Vlds = smem + 16384;
  const int tid = threadIdx.x;
  const int w = tid >> 6;              // strip 0..3
  const int l = tid & 63;
  const int lm = l & 15;
  const int lg = l >> 4;

  const int qt = (int)gridDim.x - 1 - (int)blockIdx.x;  // heavy blocks first
  const int hp = (int)blockIdx.y;      // 0..15 -> heads {2hp, 2hp+1}
  const int h0 = hp << 1;
  const int hkv = hp >> 1;             // kv head = (2hp)/4
  const int myrow = qt * QB + 16 * w + lm;  // this lane's q row

  // ---- Q fragments for both heads, pre-scaled by 1/sqrt(D) ----
  // lane holds Q[q = myrow][d = 32*c + 8*lg + j], j=0..7 contiguous
  bf16x8 qa[2][4];
  #pragma unroll
  for (int u = 0; u < 2; ++u) {
    const float* qr = q + ((size_t)((h0 + u) * SEQ + myrow)) * HD + 8 * lg;
    #pragma unroll
    for (int c = 0; c < 4; ++c) {
      float4 a = *(const float4*)(qr + 32 * c);
      float4 b = *(const float4*)(qr + 32 * c + 4);
      union { unsigned short hh[8]; bf16x8 vv; } pk;
      pk.hh[0] = f2bf(a.x * SCALE); pk.hh[1] = f2bf(a.y * SCALE);
      pk.hh[2] = f2bf(a.z * SCALE); pk.hh[3] = f2bf(a.w * SCALE);
      pk.hh[4] = f2bf(b.x * SCALE); pk.hh[5] = f2bf(b.y * SCALE);
      pk.hh[6] = f2bf(b.z * SCALE); pk.hh[7] = f2bf(b.w * SCALE);
      qa[u][c] = pk.vv;
    }
  }

  // O^T accumulators: o[u][nt2][i] = O_h[q=myrow][d = 16*nt2 + 4*lg + i]
  f32x4 o[2][8];
  #pragma unroll
  for (int u = 0; u < 2; ++u)
    #pragma unroll
    for (int i = 0; i < 8; ++i) o[u][i] = (f32x4){0.f, 0.f, 0.f, 0.f};
  float mrow[2] = {-1e30f, -1e30f};
  float lrow[2] = {0.f, 0.f};

  const int ntiles = qt + 1;
  const float* kg0 = k + (size_t)hkv * SEQ * HD;
  const float* vg0 = v + (size_t)hkv * SEQ * HD;

  for (int t = 0; t < ntiles; ++t) {
    const int kv0 = t * KVB;
    __syncthreads();  // previous tile's LDS reads complete

    // ---- stage K tile: [kv][d] bf16, b128 writes, XOR-swizzled ----
    {
      const float* kg = kg0 + (size_t)kv0 * HD;
      #pragma unroll
      for (int it = 0; it < 4; ++it) {
        int idx = it * 256 + tid;   // 0..1023
        int r = idx >> 4;           // kv row 0..63
        int c8 = (idx & 15) << 3;   // d start
        const float* src = kg + r * HD + c8;
        float4 a = *(const float4*)(src);
        float4 b = *(const float4*)(src + 4);
        union { unsigned short hh[8]; uint4 u4; } pk;
        pk.hh[0]=f2bf(a.x); pk.hh[1]=f2bf(a.y); pk.hh[2]=f2bf(a.z); pk.hh[3]=f2bf(a.w);
        pk.hh[4]=f2bf(b.x); pk.hh[5]=f2bf(b.y); pk.hh[6]=f2bf(b.z); pk.hh[7]=f2bf(b.w);
        int byte = (r << 8) + ((c8 << 1) ^ ((r & 7) << 4));
        *(uint4*)(Klds + byte) = pk.u4;
      }
      // ---- stage V^T: [d][kv] bf16, packed kv-pair b32 writes ----
      const float* vg = vg0 + (size_t)kv0 * HD;
      #pragma unroll
      for (int it = 0; it < 2; ++it) {
        int idx = it * 256 + tid;    // 0..511
        int rr = (idx & 31) << 1;    // even kv row
        int db = idx >> 5;           // d-block 0..15
        const float* s0 = vg + rr * HD + (db << 3);
        const float* s1 = s0 + HD;
        float4 a0 = *(const float4*)(s0);
        float4 b0 = *(const float4*)(s0 + 4);
        float4 a1 = *(const float4*)(s1);
        float4 b1 = *(const float4*)(s1 + 4);
        float lo[8] = {a0.x,a0.y,a0.z,a0.w,b0.x,b0.y,b0.z,b0.w};
        float hi[8] = {a1.x,a1.y,a1.z,a1.w,b1.x,b1.y,b1.z,b1.w};
        #pragma unroll
        for (int j = 0; j < 8; ++j) {
          int d = (db << 3) + j;
          int byte = (d << 7) + ((rr << 1) ^ ((d & 7) << 4));
          *(unsigned*)(Vlds + byte) = pack2bf(lo[j], hi[j]);
        }
      }
    }
    __syncthreads();

    // ---- S^T = K Q^T, both heads per K-fragment read ----
    // s[u][nt][i] = S_h[q=myrow][kv = kv0 + 16*nt + 4*lg + i]
    f32x4 s[2][4];
    #pragma unroll
    for (int u = 0; u < 2; ++u)
      #pragma unroll
      for (int nt = 0; nt < 4; ++nt) s[u][nt] = (f32x4){0.f, 0.f, 0.f, 0.f};
    #pragma unroll
    for (int nt = 0; nt < 4; ++nt) {
      int r = (nt << 4) + lm;
      #pragma unroll
      for (int kc = 0; kc < 4; ++kc) {
        int byte = (r << 8) + (((kc << 6) + (lg << 4)) ^ ((r & 7) << 4));
        bf16x8 kb = *(const bf16x8*)(Klds + byte);
        s[0][nt] = __builtin_amdgcn_mfma_f32_16x16x32_bf16(kb, qa[0][kc], s[0][nt], 0, 0, 0);
        s[1][nt] = __builtin_amdgcn_mfma_f32_16x16x32_bf16(kb, qa[1][kc], s[1][nt], 0, 0, 0);
      }
    }

    // ---- causal mask: only the diagonal tile needs it ----
    if (t == qt) {
      #pragma unroll
      for (int nt = 0; nt < 4; ++nt) {
        #pragma unroll
        for (int i = 0; i < 4; ++i) {
          int col = kv0 + (nt << 4) + (lg << 2) + i;
          float add = (col > myrow) ? NEGBIG : 0.f;
          s[0][nt][i] += add;
          s[1][nt][i] += add;
        }
      }
    }

    // ---- online softmax + in-register P B-frags, per head ----
    bf16x8 pb[2][2];
    #pragma unroll
    for (int u = 0; u < 2; ++u) {
      float tm = -1e30f;
      #pragma unroll
      for (int nt = 0; nt < 4; ++nt)
        #pragma unroll
        for (int i = 0; i < 4; ++i) tm = fmaxf(tm, s[u][nt][i]);
      tm = fmaxf(tm, __shfl_xor(tm, 16));
      tm = fmaxf(tm, __shfl_xor(tm, 32));
      float mn = fmaxf(mrow[u], tm);
      float fac = __expf(mrow[u] - mn);
      mrow[u] = mn;
      float rs = 0.f;
      #pragma unroll
      for (int nt = 0; nt < 4; ++nt) {
        #pragma unroll
        for (int i = 0; i < 4; ++i) {
          float pv = __expf(s[u][nt][i] - mn);
          s[u][nt][i] = pv;
          rs += pv;
        }
      }
      rs += __shfl_xor(rs, 16);
      rs += __shfl_xor(rs, 32);
      lrow[u] = lrow[u] * fac + rs;
      #pragma unroll
      for (int nt2 = 0; nt2 < 8; ++nt2)
        #pragma unroll
        for (int i = 0; i < 4; ++i) o[u][nt2][i] *= fac;

      // lane needs P[q=lm][kv = 32*kc + 8*lg + j], j=0..7
      unsigned pk0[4], pk1[4];
      #pragma unroll
      for (int nt = 0; nt < 4; ++nt) {
        pk0[nt] = pack2bf(s[u][nt][0], s[u][nt][1]);
        pk1[nt] = pack2bf(s[u][nt][2], s[u][nt][3]);
      }
      const int srcA = lm + ((lg & 1) << 5);  // lane group g_a = 2*(lg&1)
      const int srcB = srcA + 16;             // g_b = g_a + 1
      const bool lo2 = (lg < 2);
      #pragma unroll
      for (int kc = 0; kc < 2; ++kc) {
        int a0 = __shfl((int)pk0[2*kc], srcA), b0 = __shfl((int)pk0[2*kc+1], srcA);
        int a1 = __shfl((int)pk1[2*kc], srcA), b1 = __shfl((int)pk1[2*kc+1], srcA);
        int a2 = __shfl((int)pk0[2*kc], srcB), b2 = __shfl((int)pk0[2*kc+1], srcB);
        int a3 = __shfl((int)pk1[2*kc], srcB), b3 = __shfl((int)pk1[2*kc+1], srcB);
        union { int uu[4]; bf16x8 v; } pw;
        pw.uu[0] = lo2 ? a0 : b0;  // kv 8lg+{0,1}
        pw.uu[1] = lo2 ? a1 : b1;  // kv 8lg+{2,3}
        pw.uu[2] = lo2 ? a2 : b2;  // kv 8lg+{4,5}
        pw.uu[3] = lo2 ? a3 : b3;  // kv 8lg+{6,7}
        pb[u][kc] = pw.v;
      }
    }

    // ---- O^T += V^T P^T, both heads per V-fragment read ----
    #pragma unroll
    for (int nt2 = 0; nt2 < 8; ++nt2) {
      int dr = (nt2 << 4) + lm;
      #pragma unroll
      for (int kc = 0; kc < 2; ++kc) {
        int byte = (dr << 7) + (((kc << 6) + (lg << 4)) ^ ((dr & 7) << 4));
        bf16x8 vb = *(const bf16x8*)(Vlds + byte);
        o[0][nt2] = __builtin_amdgcn_mfma_f32_16x16x32_bf16(vb, pb[0][kc], o[0][nt2], 0, 0, 0);
        o[1][nt2] = __builtin_amdgcn_mfma_f32_16x16x32_bf16(vb, pb[1][kc], o[1][nt2], 0, 0, 0);
      }
    }
  }

  // ---- epilogue: O /= l, coalesced float4 stores, both heads ----
  #pragma unroll
  for (int u = 0; u < 2; ++u) {
    float inv = 1.f / lrow[u];
    float* orow = out + (size_t)myrow * ODIM + (h0 + u) * HD + (lg << 2);
    #pragma unroll
    for (int nt2 = 0; nt2 < 8; ++nt2) {
      float4 st = {o[u][nt2][0] * inv, o[u][nt2][1] * inv,
                   o[u][nt2][2] * inv, o[u][nt2][3] * inv};
      *(float4*)(orow + (nt2 << 4)) = st;
    }
  }
}

extern "C" void kernel_launch(void* const* d_in, const int* in_sizes, int n_in,
                              void* d_out, int out_size, void* d_ws, size_t ws_size,
                              hipStream_t stream) {
  // inputs: [0]=input_pos(i64) [1]=q(f32) [2]=k(f32) [3]=v(f32)
  //         [4]=bsz [5]=seqlen [6]=mask(f32, pure causal -> computed analytically)
  const float* q = (const float*)d_in[1];
  const float* k = (const float*)d_in[2];
  const float* v = (const float*)d_in[3];
  float* out = (float*)d_out;
  dim3 grid(SEQ / QB, NH / 2);  // 32 Q-tiles x 16 head-pairs = 512 blocks
  sdpa_flash_kernel<<<grid, 256, 0, stream>>>(q, k, v, out);
}

// Round 12
// 99.696 us; speedup vs baseline: 3.2477x; 1.6963x over previous
//
#include <hip/hip_runtime.h>
#include <hip/hip_bf16.h>

#define SEQ 2048
#define HD 128
#define NH 32
#define NKV 8
#define ODIM 4096
#define QB 64
#define KVB 64
#define SCALE 0.08838834764831845f
#define NEGBIG -1e9f

typedef __attribute__((ext_vector_type(8))) short bf16x8;
typedef __attribute__((ext_vector_type(4))) float f32x4;

__device__ __forceinline__ unsigned short f2bf(float x) {
  union { __hip_bfloat16 b; unsigned short u; } c;
  c.b = __float2bfloat16(x);  // RNE, single HW cvt
  return c.u;
}

__device__ __forceinline__ unsigned pack2bf(float lo, float hi) {
  union { __hip_bfloat162 h; unsigned u; } c;
  c.h = __float22bfloat162_rn(float2{lo, hi});  // x=lo (low 16b), y=hi
  return c.u;
}

// r8 geometry (best known: 105us) + double-buffered KV pipeline.
// Block p,h: 8 waves, Q-tiles {p, 31-p} (w<4 -> A, w>=4 -> B), 33 units each.
// Pipeline per tile: issue global loads(t+1) -> compute(t) from buf[cur]
// -> cvt+ds_write into buf[cur^1] -> ONE barrier. Load latency hides under
// compute; staging state is 8 individually-named float4 (macro-expanded,
// no lambdas/arrays -> no scratch). LDS 2x32KB -> 2 blocks/CU.
// Swapped-operand MFMA: S^T = mfma(K, Q), O^T = mfma(V, P); lane owns one
// P-row; softmax stats scalar; P stays in registers.
__global__ __launch_bounds__(512, 4) void sdpa_flash_kernel(
    const float* __restrict__ q, const float* __restrict__ k,
    const float* __restrict__ v, float* __restrict__ out) {
  // buffer b: K [64][128] bf16 swz at smem+b*32768, V^T [128][64] at +16384
  __shared__ __align__(16) unsigned char smem[65536];
  const int tid = threadIdx.x;
  const int w = tid >> 6;
  const int l = tid & 63;
  const int lm = l & 15;
  const int lg = l >> 4;

  const int p = (int)blockIdx.x;       // 0..15
  const int qtA = p;
  const int qtB = 31 - p;
  const int myqt = (w < 4) ? qtA : qtB;
  const int h = (int)blockIdx.y;
  const int hkv = h >> 2;              // repeat_interleave: kv head = h / 4
  const int qbase = myqt * QB + 16 * (w & 3);
  const int myrow = qbase + lm;        // this lane's q row

  // ---- Q fragments, pre-scaled by 1/sqrt(D) ----
  bf16x8 qa[4];
  {
    const float* qr = q + ((size_t)(h * SEQ + myrow)) * HD + 8 * lg;
    #pragma unroll
    for (int c = 0; c < 4; ++c) {
      float4 a = *(const float4*)(qr + 32 * c);
      float4 b = *(const float4*)(qr + 32 * c + 4);
      union { unsigned short hh[8]; bf16x8 vv; } pk;
      pk.hh[0] = f2bf(a.x * SCALE); pk.hh[1] = f2bf(a.y * SCALE);
      pk.hh[2] = f2bf(a.z * SCALE); pk.hh[3] = f2bf(a.w * SCALE);
      pk.hh[4] = f2bf(b.x * SCALE); pk.hh[5] = f2bf(b.y * SCALE);
      pk.hh[6] = f2bf(b.z * SCALE); pk.hh[7] = f2bf(b.w * SCALE);
      qa[c] = pk.vv;
    }
  }

  f32x4 o[8];
  #pragma unroll
  for (int i = 0; i < 8; ++i) o[i] = (f32x4){0.f, 0.f, 0.f, 0.f};
  float mrow = -1e30f;
  float lrow = 0.f;

  const int ntiles = qtB + 1;
  const float* kg0 = k + (size_t)hkv * SEQ * HD;
  const float* vg0 = v + (size_t)hkv * SEQ * HD;

  // per-thread staging coordinates (constant across tiles)
  const int k_r0 = tid >> 4;           // K rows k_r0, k_r0+32
  const int k_c8 = (tid & 15) << 3;    // K d-start
  const int v_rr = (tid & 31) << 1;    // V even kv row
  const int v_d0 = (tid >> 5) << 3;    // V d-block start

  float4 ka0, kb0, ka1, kb1, va0, vb0, va1, vb1;

#define LOADT(tt) {                                                          \
    const float* kg_ = kg0 + (size_t)((tt) * KVB) * HD + k_r0 * HD + k_c8;   \
    ka0 = *(const float4*)(kg_);                                             \
    kb0 = *(const float4*)(kg_ + 4);                                         \
    ka1 = *(const float4*)(kg_ + 32 * HD);                                   \
    kb1 = *(const float4*)(kg_ + 32 * HD + 4);                               \
    const float* vg_ = vg0 + (size_t)((tt) * KVB) * HD + v_rr * HD + v_d0;   \
    va0 = *(const float4*)(vg_);                                             \
    vb0 = *(const float4*)(vg_ + 4);                                         \
    va1 = *(const float4*)(vg_ + HD);                                        \
    vb1 = *(const float4*)(vg_ + HD + 4);                                    \
  }

#define WRITELDS(bufbase) {                                                  \
    unsigned char* Kb_ = (bufbase);                                          \
    unsigned char* Vb_ = (bufbase) + 16384;                                  \
    {                                                                        \
      union { unsigned short hh[8]; uint4 u4; } pk_;                         \
      pk_.hh[0]=f2bf(ka0.x); pk_.hh[1]=f2bf(ka0.y);                          \
      pk_.hh[2]=f2bf(ka0.z); pk_.hh[3]=f2bf(ka0.w);                          \
      pk_.hh[4]=f2bf(kb0.x); pk_.hh[5]=f2bf(kb0.y);                          \
      pk_.hh[6]=f2bf(kb0.z); pk_.hh[7]=f2bf(kb0.w);                          \
      int byte_ = (k_r0 << 8) + ((k_c8 << 1) ^ ((k_r0 & 7) << 4));           \
      *(uint4*)(Kb_ + byte_) = pk_.u4;                                       \
    }                                                                        \
    {                                                                        \
      int r1_ = k_r0 + 32;                                                   \
      union { unsigned short hh[8]; uint4 u4; } pk_;                         \
      pk_.hh[0]=f2bf(ka1.x); pk_.hh[1]=f2bf(ka1.y);                          \
      pk_.hh[2]=f2bf(ka1.z); pk_.hh[3]=f2bf(ka1.w);                          \
      pk_.hh[4]=f2bf(kb1.x); pk_.hh[5]=f2bf(kb1.y);                          \
      pk_.hh[6]=f2bf(kb1.z); pk_.hh[7]=f2bf(kb1.w);                          \
      int byte_ = (r1_ << 8) + ((k_c8 << 1) ^ ((r1_ & 7) << 4));             \
      *(uint4*)(Kb_ + byte_) = pk_.u4;                                       \
    }                                                                        \
    {                                                                        \
      unsigned w0_ = pack2bf(va0.x, va1.x), w1_ = pack2bf(va0.y, va1.y);     \
      unsigned w2_ = pack2bf(va0.z, va1.z), w3_ = pack2bf(va0.w, va1.w);     \
      unsigned w4_ = pack2bf(vb0.x, vb1.x), w5_ = pack2bf(vb0.y, vb1.y);     \
      unsigned w6_ = pack2bf(vb0.z, vb1.z), w7_ = pack2bf(vb0.w, vb1.w);     \
      int rb_ = v_rr << 1;                                                   \
      int d_;                                                                \
      d_ = v_d0;     *(unsigned*)(Vb_ + (d_ << 7) + (rb_ ^ ((d_ & 7) << 4))) = w0_; \
      d_ = v_d0 + 1; *(unsigned*)(Vb_ + (d_ << 7) + (rb_ ^ ((d_ & 7) << 4))) = w1_; \
      d_ = v_d0 + 2; *(unsigned*)(Vb_ + (d_ << 7) + (rb_ ^ ((d_ & 7) << 4))) = w2_; \
      d_ = v_d0 + 3; *(unsigned*)(Vb_ + (d_ << 7) + (rb_ ^ ((d_ & 7) << 4))) = w3_; \
      d_ = v_d0 + 4; *(unsigned*)(Vb_ + (d_ << 7) + (rb_ ^ ((d_ & 7) << 4))) = w4_; \
      d_ = v_d0 + 5; *(unsigned*)(Vb_ + (d_ << 7) + (rb_ ^ ((d_ & 7) << 4))) = w5_; \
      d_ = v_d0 + 6; *(unsigned*)(Vb_ + (d_ << 7) + (rb_ ^ ((d_ & 7) << 4))) = w6_; \
      d_ = v_d0 + 7; *(unsigned*)(Vb_ + (d_ << 7) + (rb_ ^ ((d_ & 7) << 4))) = w7_; \
    }                                                                        \
  }

  // ---- prologue: stage tile 0 into buffer 0 ----
  LOADT(0);
  WRITELDS(smem);
  __syncthreads();
  int cur = 0;

  for (int t = 0; t < ntiles; ++t) {
    const int kv0 = t * KVB;
    const bool have_next = (t + 1 < ntiles);
    if (have_next) LOADT(t + 1);  // latency hides under compute below

    unsigned char* Klds = smem + (cur << 15);
    unsigned char* Vlds = Klds + 16384;

    if (t <= myqt) {  // wave-uniform guard; A-waves idle past their diagonal
      // ---- S^T = K Q^T : s[nt][i] = S[q=lm][kv = kv0 + 16*nt + 4*lg + i] ----
      f32x4 s[4];
      #pragma unroll
      for (int nt = 0; nt < 4; ++nt) s[nt] = (f32x4){0.f, 0.f, 0.f, 0.f};
      #pragma unroll
      for (int nt = 0; nt < 4; ++nt) {
        int r = (nt << 4) + lm;
        #pragma unroll
        for (int kc = 0; kc < 4; ++kc) {
          int byte = (r << 8) + (((kc << 6) + (lg << 4)) ^ ((r & 7) << 4));
          bf16x8 kb = *(const bf16x8*)(Klds + byte);
          s[nt] = __builtin_amdgcn_mfma_f32_16x16x32_bf16(kb, qa[kc], s[nt], 0, 0, 0);
        }
      }

      // ---- causal mask (additive -1e9 like the reference) ----
      if (kv0 + KVB - 1 > qbase) {
        #pragma unroll
        for (int nt = 0; nt < 4; ++nt) {
          #pragma unroll
          for (int i = 0; i < 4; ++i) {
            int col = kv0 + (nt << 4) + (lg << 2) + i;
            s[nt][i] += (col > myrow) ? NEGBIG : 0.f;
          }
        }
      }

      // ---- online softmax: lane owns row q=lm; reduce over 4 lanes ----
      float tm = -1e30f;
      #pragma unroll
      for (int nt = 0; nt < 4; ++nt)
        #pragma unroll
        for (int i = 0; i < 4; ++i) tm = fmaxf(tm, s[nt][i]);
      tm = fmaxf(tm, __shfl_xor(tm, 16));
      tm = fmaxf(tm, __shfl_xor(tm, 32));
      float mn = fmaxf(mrow, tm);
      float fac = __expf(mrow - mn);
      mrow = mn;
      float rs = 0.f;
      #pragma unroll
      for (int nt = 0; nt < 4; ++nt) {
        #pragma unroll
        for (int i = 0; i < 4; ++i) {
          float pv = __expf(s[nt][i] - mn);
          s[nt][i] = pv;
          rs += pv;
        }
      }
      rs += __shfl_xor(rs, 16);
      rs += __shfl_xor(rs, 32);
      lrow = lrow * fac + rs;
      #pragma unroll
      for (int nt2 = 0; nt2 < 8; ++nt2) {
        #pragma unroll
        for (int i = 0; i < 4; ++i) o[nt2][i] *= fac;
      }

      // ---- P^T B-frags fully in-register via pack + lane exchange ----
      unsigned pk0[4], pk1[4];
      #pragma unroll
      for (int nt = 0; nt < 4; ++nt) {
        pk0[nt] = pack2bf(s[nt][0], s[nt][1]);
        pk1[nt] = pack2bf(s[nt][2], s[nt][3]);
      }
      const int srcA = lm + ((lg & 1) << 5);  // lane group g_a = 2*(lg&1)
      const int srcB = srcA + 16;             // g_b = g_a + 1
      const bool lo2 = (lg < 2);
      bf16x8 pb[2];
      #pragma unroll
      for (int kc = 0; kc < 2; ++kc) {
        int a0 = __shfl((int)pk0[2*kc], srcA), b0 = __shfl((int)pk0[2*kc+1], srcA);
        int a1 = __shfl((int)pk1[2*kc], srcA), b1 = __shfl((int)pk1[2*kc+1], srcA);
        int a2 = __shfl((int)pk0[2*kc], srcB), b2 = __shfl((int)pk0[2*kc+1], srcB);
        int a3 = __shfl((int)pk1[2*kc], srcB), b3 = __shfl((int)pk1[2*kc+1], srcB);
        union { int uu[4]; bf16x8 v; } pw;
        pw.uu[0] = lo2 ? a0 : b0;  // kv 8lg+{0,1}
        pw.uu[1] = lo2 ? a1 : b1;  // kv 8lg+{2,3}
        pw.uu[2] = lo2 ? a2 : b2;  // kv 8lg+{4,5}
        pw.uu[3] = lo2 ? a3 : b3;  // kv 8lg+{6,7}
        pb[kc] = pw.v;
      }

      // ---- O^T += V^T P^T  (V^T in LDS feeds the A operand) ----
      #pragma unroll
      for (int nt2 = 0; nt2 < 8; ++nt2) {
        int dr = (nt2 << 4) + lm;
        #pragma unroll
        for (int kc = 0; kc < 2; ++kc) {
          int byte = (dr << 7) + (((kc << 6) + (lg << 4)) ^ ((dr & 7) << 4));
          bf16x8 vb = *(const bf16x8*)(Vlds + byte);
          o[nt2] = __builtin_amdgcn_mfma_f32_16x16x32_bf16(vb, pb[kc], o[nt2], 0, 0, 0);
        }
      }
    }

    if (have_next) {
      // stage tile t+1 into the other buffer; it was last read at tile t-1,
      // whose compute finished before the previous barrier
      WRITELDS(smem + ((cur ^ 1) << 15));
    }
    __syncthreads();
    cur ^= 1;
  }

  // ---- epilogue: O /= l, coalesced float4 stores ----
  float inv = 1.f / lrow;
  float* orow = out + (size_t)myrow * ODIM + h * HD + (lg << 2);
  #pragma unroll
  for (int nt2 = 0; nt2 < 8; ++nt2) {
    float4 st = {o[nt2][0] * inv, o[nt2][1] * inv, o[nt2][2] * inv, o[nt2][3] * inv};
    *(float4*)(orow + (nt2 << 4)) = st;
  }
}

extern "C" void kernel_launch(void* const* d_in, const int* in_sizes, int n_in,
                              void* d_out, int out_size, void* d_ws, size_t ws_size,
                              hipStream_t stream) {
  // inputs: [0]=input_pos(i64) [1]=q(f32) [2]=k(f32) [3]=v(f32)
  //         [4]=bsz [5]=seqlen [6]=mask(f32, pure causal -> computed analytically)
  const float* q = (const float*)d_in[1];
  const float* k = (const float*)d_in[2];
  const float* v = (const float*)d_in[3];
  float* out = (float*)d_out;
  dim3 grid(SEQ / QB / 2, NH);  // 16 balanced Q-tile pairs x 32 heads
  sdpa_flash_kernel<<<grid, 512, 0, stream>>>(q, k, v, out);
}

// Round 13
// 86.263 us; speedup vs baseline: 3.7535x; 1.1557x over previous
//
#include <hip/hip_runtime.h>
#include <hip/hip_bf16.h>

#define SEQ 2048
#define HD 128
#define NH 32
#define NKV 8
#define ODIM 4096
#define QB 64
#define KVB 64
#define SCALE 0.08838834764831845f
#define NEGBIG -1e9f

typedef __attribute__((ext_vector_type(8))) short bf16x8;
typedef __attribute__((ext_vector_type(4))) float f32x4;

__device__ __forceinline__ unsigned short f2bf(float x) {
  union { __hip_bfloat16 b; unsigned short u; } c;
  c.b = __float2bfloat16(x);
  return c.u;
}

__device__ __forceinline__ unsigned pack2bf(float lo, float hi) {
  union { __hip_bfloat162 h; unsigned u; } c;
  c.h = __float22bfloat162_rn(float2{lo, hi});
  return c.u;
}

__device__ __forceinline__ void gload_lds16(const unsigned char* g, unsigned char* l) {
  __builtin_amdgcn_global_load_lds(
      (const __attribute__((address_space(1))) void*)g,
      (__attribute__((address_space(3))) void*)l, 16, 0, 0);
}

// ---------- prepass: K/V f32 -> pre-swizzled bf16 tile images in d_ws ----------
// Kimg[hkv][t]: 16KB image, byte (r<<8) + ((2d) ^ ((r&7)<<4))  [r=kv 0..63]
// Vimg[hkv][t]: 16KB image, byte (d<<7) + ((2kv) ^ ((d&7)<<4)) [kv pairs packed]
#define KWORK (NKV * SEQ * 16)          // 262144 units: 8 bf16 each
#define VWORK (NKV * (SEQ / 2) * 16)    // 131072 units: 8 x bf162 each
__global__ __launch_bounds__(256) void sdpa_prepass(
    const float* __restrict__ k, const float* __restrict__ v,
    unsigned char* __restrict__ ws) {
  unsigned char* kimg = ws;
  unsigned char* vimg = ws + (NKV * 32 * 16384);
  int idx = (int)blockIdx.x * 256 + (int)threadIdx.x;
  if (idx < KWORK) {
    int hkv = idx >> 15;            // /32768
    int rem = idx & 32767;
    int rg = rem >> 4;              // global kv row 0..2047
    int c8 = (rem & 15) << 3;       // d start
    const float* src = k + ((size_t)hkv * SEQ + rg) * HD + c8;
    float4 a = *(const float4*)(src);
    float4 b = *(const float4*)(src + 4);
    union { unsigned short hh[8]; uint4 u4; } pk;
    pk.hh[0]=f2bf(a.x); pk.hh[1]=f2bf(a.y); pk.hh[2]=f2bf(a.z); pk.hh[3]=f2bf(a.w);
    pk.hh[4]=f2bf(b.x); pk.hh[5]=f2bf(b.y); pk.hh[6]=f2bf(b.z); pk.hh[7]=f2bf(b.w);
    int t = rg >> 6, r = rg & 63;
    size_t base = ((size_t)(hkv * 32 + t)) << 14;
    *(uint4*)(kimg + base + (r << 8) + ((c8 << 1) ^ ((r & 7) << 4))) = pk.u4;
  } else {
    int u = idx - KWORK;
    if (u >= VWORK) return;
    int hkv = u >> 14;              // /16384
    int rem = u & 16383;
    int pr = rem >> 4;              // pair-row 0..1023
    int d0 = (rem & 15) << 3;
    int rg = pr << 1;               // even global kv row
    const float* s0 = v + ((size_t)hkv * SEQ + rg) * HD + d0;
    const float* s1 = s0 + HD;
    float4 a0 = *(const float4*)(s0);
    float4 b0 = *(const float4*)(s0 + 4);
    float4 a1 = *(const float4*)(s1);
    float4 b1 = *(const float4*)(s1 + 4);
    float lo[8] = {a0.x,a0.y,a0.z,a0.w,b0.x,b0.y,b0.z,b0.w};
    float hi[8] = {a1.x,a1.y,a1.z,a1.w,b1.x,b1.y,b1.z,b1.w};
    int t = rg >> 6, rr = rg & 63;
    size_t base = ((size_t)(hkv * 32 + t)) << 14;
    int rb = rr << 1;
    #pragma unroll
    for (int j = 0; j < 8; ++j) {
      int d = d0 + j;
      *(unsigned*)(vimg + base + (d << 7) + (rb ^ ((d & 7) << 4))) =
          pack2bf(lo[j], hi[j]);
    }
  }
}

// ---------- main: r12 structure, staging = global_load_lds identity DMA ----------
__global__ __launch_bounds__(512, 4) void sdpa_flash_kernel(
    const float* __restrict__ q, const unsigned char* __restrict__ kimg,
    const unsigned char* __restrict__ vimg, float* __restrict__ out) {
  __shared__ __align__(16) unsigned char smem[65536];
  const int tid = threadIdx.x;
  const int w = tid >> 6;
  const int l = tid & 63;
  const int lm = l & 15;
  const int lg = l >> 4;

  const int p = (int)blockIdx.x;
  const int qtA = p;
  const int qtB = 31 - p;
  const int myqt = (w < 4) ? qtA : qtB;
  const int h = (int)blockIdx.y;
  const int hkv = h >> 2;
  const int qbase = myqt * QB + 16 * (w & 3);
  const int myrow = qbase + lm;

  bf16x8 qa[4];
  {
    const float* qr = q + ((size_t)(h * SEQ + myrow)) * HD + 8 * lg;
    #pragma unroll
    for (int c = 0; c < 4; ++c) {
      float4 a = *(const float4*)(qr + 32 * c);
      float4 b = *(const float4*)(qr + 32 * c + 4);
      union { unsigned short hh[8]; bf16x8 vv; } pk;
      pk.hh[0] = f2bf(a.x * SCALE); pk.hh[1] = f2bf(a.y * SCALE);
      pk.hh[2] = f2bf(a.z * SCALE); pk.hh[3] = f2bf(a.w * SCALE);
      pk.hh[4] = f2bf(b.x * SCALE); pk.hh[5] = f2bf(b.y * SCALE);
      pk.hh[6] = f2bf(b.z * SCALE); pk.hh[7] = f2bf(b.w * SCALE);
      qa[c] = pk.vv;
    }
  }

  f32x4 o[8];
  #pragma unroll
  for (int i = 0; i < 8; ++i) o[i] = (f32x4){0.f, 0.f, 0.f, 0.f};
  float mrow = -1e30f;
  float lrow = 0.f;

  const int ntiles = qtB + 1;
  const unsigned char* kt0 = kimg + (((size_t)(hkv * 32)) << 14);
  const unsigned char* vt0 = vimg + (((size_t)(hkv * 32)) << 14);
  const int woff = w << 10;  // wave's 1KB slice within each 8KB chunk

#define STAGE(tt, bufbase) {                                                 \
    const unsigned char* ks_ = kt0 + (((size_t)(tt)) << 14);                 \
    const unsigned char* vs_ = vt0 + (((size_t)(tt)) << 14);                 \
    unsigned char* Kb_ = (bufbase);                                          \
    unsigned char* Vb_ = (bufbase) + 16384;                                  \
    gload_lds16(ks_ + woff + (l << 4), Kb_ + woff);                          \
    gload_lds16(ks_ + 8192 + woff + (l << 4), Kb_ + 8192 + woff);            \
    gload_lds16(vs_ + woff + (l << 4), Vb_ + woff);                          \
    gload_lds16(vs_ + 8192 + woff + (l << 4), Vb_ + 8192 + woff);            \
  }

  STAGE(0, smem);
  __syncthreads();  // drains vmcnt -> tile 0 resident
  int cur = 0;

  for (int t = 0; t < ntiles; ++t) {
    const int kv0 = t * KVB;
    if (t + 1 < ntiles) STAGE(t + 1, smem + ((cur ^ 1) << 15));  // async DMA

    unsigned char* Klds = smem + (cur << 15);
    unsigned char* Vlds = Klds + 16384;

    if (t <= myqt) {
      f32x4 s[4];
      #pragma unroll
      for (int nt = 0; nt < 4; ++nt) s[nt] = (f32x4){0.f, 0.f, 0.f, 0.f};
      __builtin_amdgcn_s_setprio(1);
      #pragma unroll
      for (int nt = 0; nt < 4; ++nt) {
        int r = (nt << 4) + lm;
        #pragma unroll
        for (int kc = 0; kc < 4; ++kc) {
          int byte = (r << 8) + (((kc << 6) + (lg << 4)) ^ ((r & 7) << 4));
          bf16x8 kb = *(const bf16x8*)(Klds + byte);
          s[nt] = __builtin_amdgcn_mfma_f32_16x16x32_bf16(kb, qa[kc], s[nt], 0, 0, 0);
        }
      }
      __builtin_amdgcn_s_setprio(0);

      if (kv0 + KVB - 1 > qbase) {
        #pragma unroll
        for (int nt = 0; nt < 4; ++nt) {
          #pragma unroll
          for (int i = 0; i < 4; ++i) {
            int col = kv0 + (nt << 4) + (lg << 2) + i;
            s[nt][i] += (col > myrow) ? NEGBIG : 0.f;
          }
        }
      }

      float tm = -1e30f;
      #pragma unroll
      for (int nt = 0; nt < 4; ++nt)
        #pragma unroll
        for (int i = 0; i < 4; ++i) tm = fmaxf(tm, s[nt][i]);
      tm = fmaxf(tm, __shfl_xor(tm, 16));
      tm = fmaxf(tm, __shfl_xor(tm, 32));
      float mn = fmaxf(mrow, tm);
      float fac = __expf(mrow - mn);
      mrow = mn;
      float rs = 0.f;
      #pragma unroll
      for (int nt = 0; nt < 4; ++nt) {
        #pragma unroll
        for (int i = 0; i < 4; ++i) {
          float pv = __expf(s[nt][i] - mn);
          s[nt][i] = pv;
          rs += pv;
        }
      }
      rs += __shfl_xor(rs, 16);
      rs += __shfl_xor(rs, 32);
      lrow = lrow * fac + rs;
      #pragma unroll
      for (int nt2 = 0; nt2 < 8; ++nt2) {
        #pragma unroll
        for (int i = 0; i < 4; ++i) o[nt2][i] *= fac;
      }

      unsigned pk0[4], pk1[4];
      #pragma unroll
      for (int nt = 0; nt < 4; ++nt) {
        pk0[nt] = pack2bf(s[nt][0], s[nt][1]);
        pk1[nt] = pack2bf(s[nt][2], s[nt][3]);
      }
      const int srcA = lm + ((lg & 1) << 5);
      const int srcB = srcA + 16;
      const bool lo2 = (lg < 2);
      bf16x8 pb[2];
      #pragma unroll
      for (int kc = 0; kc < 2; ++kc) {
        int a0 = __shfl((int)pk0[2*kc], srcA), b0 = __shfl((int)pk0[2*kc+1], srcA);
        int a1 = __shfl((int)pk1[2*kc], srcA), b1 = __shfl((int)pk1[2*kc+1], srcA);
        int a2 = __shfl((int)pk0[2*kc], srcB), b2 = __shfl((int)pk0[2*kc+1], srcB);
        int a3 = __shfl((int)pk1[2*kc], srcB), b3 = __shfl((int)pk1[2*kc+1], srcB);
        union { int uu[4]; bf16x8 v; } pw;
        pw.uu[0] = lo2 ? a0 : b0;
        pw.uu[1] = lo2 ? a1 : b1;
        pw.uu[2] = lo2 ? a2 : b2;
        pw.uu[3] = lo2 ? a3 : b3;
        pb[kc] = pw.v;
      }

      __builtin_amdgcn_s_setprio(1);
      #pragma unroll
      for (int nt2 = 0; nt2 < 8; ++nt2) {
        int dr = (nt2 << 4) + lm;
        #pragma unroll
        for (int kc = 0; kc < 2; ++kc) {
          int byte = (dr << 7) + (((kc << 6) + (lg << 4)) ^ ((dr & 7) << 4));
          bf16x8 vb = *(const bf16x8*)(Vlds + byte);
          o[nt2] = __builtin_amdgcn_mfma_f32_16x16x32_bf16(vb, pb[kc], o[nt2], 0, 0, 0);
        }
      }
      __builtin_amdgcn_s_setprio(0);
    }

    __syncthreads();  // drains vmcnt -> tile t+1 resident in buf^1
    cur ^= 1;
  }

  float inv = 1.f / lrow;
  float* orow = out + (size_t)myrow * ODIM + h * HD + (lg << 2);
  #pragma unroll
  for (int nt2 = 0; nt2 < 8; ++nt2) {
    float4 st = {o[nt2][0] * inv, o[nt2][1] * inv, o[nt2][2] * inv, o[nt2][3] * inv};
    *(float4*)(orow + (nt2 << 4)) = st;
  }
#undef STAGE
}

// ---------- fallback (r12 verbatim): used when ws_size is too small ----------
__global__ __launch_bounds__(512, 4) void sdpa_flash_fb(
    const float* __restrict__ q, const float* __restrict__ k,
    const float* __restrict__ v, float* __restrict__ out) {
  __shared__ __align__(16) unsigned char smem[65536];
  const int tid = threadIdx.x;
  const int w = tid >> 6;
  const int l = tid & 63;
  const int lm = l & 15;
  const int lg = l >> 4;
  const int p = (int)blockIdx.x;
  const int qtA = p;
  const int qtB = 31 - p;
  const int myqt = (w < 4) ? qtA : qtB;
  const int h = (int)blockIdx.y;
  const int hkv = h >> 2;
  const int qbase = myqt * QB + 16 * (w & 3);
  const int myrow = qbase + lm;
  bf16x8 qa[4];
  {
    const float* qr = q + ((size_t)(h * SEQ + myrow)) * HD + 8 * lg;
    #pragma unroll
    for (int c = 0; c < 4; ++c) {
      float4 a = *(const float4*)(qr + 32 * c);
      float4 b = *(const float4*)(qr + 32 * c + 4);
      union { unsigned short hh[8]; bf16x8 vv; } pk;
      pk.hh[0] = f2bf(a.x * SCALE); pk.hh[1] = f2bf(a.y * SCALE);
      pk.hh[2] = f2bf(a.z * SCALE); pk.hh[3] = f2bf(a.w * SCALE);
      pk.hh[4] = f2bf(b.x * SCALE); pk.hh[5] = f2bf(b.y * SCALE);
      pk.hh[6] = f2bf(b.z * SCALE); pk.hh[7] = f2bf(b.w * SCALE);
      qa[c] = pk.vv;
    }
  }
  f32x4 o[8];
  #pragma unroll
  for (int i = 0; i < 8; ++i) o[i] = (f32x4){0.f, 0.f, 0.f, 0.f};
  float mrow = -1e30f;
  float lrow = 0.f;
  const int ntiles = qtB + 1;
  const float* kg0 = k + (size_t)hkv * SEQ * HD;
  const float* vg0 = v + (size_t)hkv * SEQ * HD;
  const int k_r0 = tid >> 4;
  const int k_c8 = (tid & 15) << 3;
  const int v_rr = (tid & 31) << 1;
  const int v_d0 = (tid >> 5) << 3;
  float4 ka0, kb0, ka1, kb1, va0, vb0, va1, vb1;
#define LOADT(tt) {                                                          \
    const float* kg_ = kg0 + (size_t)((tt) * KVB) * HD + k_r0 * HD + k_c8;   \
    ka0 = *(const float4*)(kg_);                                             \
    kb0 = *(const float4*)(kg_ + 4);                                         \
    ka1 = *(const float4*)(kg_ + 32 * HD);                                   \
    kb1 = *(const float4*)(kg_ + 32 * HD + 4);                               \
    const float* vg_ = vg0 + (size_t)((tt) * KVB) * HD + v_rr * HD + v_d0;   \
    va0 = *(const float4*)(vg_);                                             \
    vb0 = *(const float4*)(vg_ + 4);                                         \
    va1 = *(const float4*)(vg_ + HD);                                        \
    vb1 = *(const float4*)(vg_ + HD + 4);                                    \
  }
#define WRITELDS(bufbase) {                                                  \
    unsigned char* Kb_ = (bufbase);                                          \
    unsigned char* Vb_ = (bufbase) + 16384;                                  \
    {                                                                        \
      union { unsigned short hh[8]; uint4 u4; } pk_;                         \
      pk_.hh[0]=f2bf(ka0.x); pk_.hh[1]=f2bf(ka0.y);                          \
      pk_.hh[2]=f2bf(ka0.z); pk_.hh[3]=f2bf(ka0.w);                          \
      pk_.hh[4]=f2bf(kb0.x); pk_.hh[5]=f2bf(kb0.y);                          \
      pk_.hh[6]=f2bf(kb0.z); pk_.hh[7]=f2bf(kb0.w);                          \
      int byte_ = (k_r0 << 8) + ((k_c8 << 1) ^ ((k_r0 & 7) << 4));           \
      *(uint4*)(Kb_ + byte_) = pk_.u4;                                       \
    }                                                                        \
    {                                                                        \
      int r1_ = k_r0 + 32;                                                   \
      union { unsigned short hh[8]; uint4 u4; } pk_;                         \
      pk_.hh[0]=f2bf(ka1.x); pk_.hh[1]=f2bf(ka1.y);                          \
      pk_.hh[2]=f2bf(ka1.z); pk_.hh[3]=f2bf(ka1.w);                          \
      pk_.hh[4]=f2bf(kb1.x); pk_.hh[5]=f2bf(kb1.y);                          \
      pk_.hh[6]=f2bf(kb1.z); pk_.hh[7]=f2bf(kb1.w);                          \
      int byte_ = (r1_ << 8) + ((k_c8 << 1) ^ ((r1_ & 7) << 4));             \
      *(uint4*)(Kb_ + byte_) = pk_.u4;                                       \
    }                                                                        \
    {                                                                        \
      unsigned w0_ = pack2bf(va0.x, va1.x), w1_ = pack2bf(va0.y, va1.y);     \
      unsigned w2_ = pack2bf(va0.z, va1.z), w3_ = pack2bf(va0.w, va1.w);     \
      unsigned w4_ = pack2bf(vb0.x, vb1.x), w5_ = pack2bf(vb0.y, vb1.y);     \
      unsigned w6_ = pack2bf(vb0.z, vb1.z), w7_ = pack2bf(vb0.w, vb1.w);     \
      int rb_ = v_rr << 1;                                                   \
      int d_;                                                                \
      d_ = v_d0;     *(unsigned*)(Vb_ + (d_ << 7) + (rb_ ^ ((d_ & 7) << 4))) = w0_; \
      d_ = v_d0 + 1; *(unsigned*)(Vb_ + (d_ << 7) + (rb_ ^ ((d_ & 7) << 4))) = w1_; \
      d_ = v_d0 + 2; *(unsigned*)(Vb_ + (d_ << 7) + (rb_ ^ ((d_ & 7) << 4))) = w2_; \
      d_ = v_d0 + 3; *(unsigned*)(Vb_ + (d_ << 7) + (rb_ ^ ((d_ & 7) << 4))) = w3_; \
      d_ = v_d0 + 4; *(unsigned*)(Vb_ + (d_ << 7) + (rb_ ^ ((d_ & 7) << 4))) = w4_; \
      d_ = v_d0 + 5; *(unsigned*)(Vb_ + (d_ << 7) + (rb_ ^ ((d_ & 7) << 4))) = w5_; \
      d_ = v_d0 + 6; *(unsigned*)(Vb_ + (d_ << 7) + (rb_ ^ ((d_ & 7) << 4))) = w6_; \
      d_ = v_d0 + 7; *(unsigned*)(Vb_ + (d_ << 7) + (rb_ ^ ((d_ & 7) << 4))) = w7_; \
    }                                                                        \
  }
  LOADT(0);
  WRITELDS(smem);
  __syncthreads();
  int cur = 0;
  for (int t = 0; t < ntiles; ++t) {
    const int kv0 = t * KVB;
    const bool have_next = (t + 1 < ntiles);
    if (have_next) LOADT(t + 1);
    unsigned char* Klds = smem + (cur << 15);
    unsigned char* Vlds = Klds + 16384;
    if (t <= myqt) {
      f32x4 s[4];
      #pragma unroll
      for (int nt = 0; nt < 4; ++nt) s[nt] = (f32x4){0.f, 0.f, 0.f, 0.f};
      #pragma unroll
      for (int nt = 0; nt < 4; ++nt) {
        int r = (nt << 4) + lm;
        #pragma unroll
        for (int kc = 0; kc < 4; ++kc) {
          int byte = (r << 8) + (((kc << 6) + (lg << 4)) ^ ((r & 7) << 4));
          bf16x8 kb = *(const bf16x8*)(Klds + byte);
          s[nt] = __builtin_amdgcn_mfma_f32_16x16x32_bf16(kb, qa[kc], s[nt], 0, 0, 0);
        }
      }
      if (kv0 + KVB - 1 > qbase) {
        #pragma unroll
        for (int nt = 0; nt < 4; ++nt) {
          #pragma unroll
          for (int i = 0; i < 4; ++i) {
            int col = kv0 + (nt << 4) + (lg << 2) + i;
            s[nt][i] += (col > myrow) ? NEGBIG : 0.f;
          }
        }
      }
      float tm = -1e30f;
      #pragma unroll
      for (int nt = 0; nt < 4; ++nt)
        #pragma unroll
        for (int i = 0; i < 4; ++i) tm = fmaxf(tm, s[nt][i]);
      tm = fmaxf(tm, __shfl_xor(tm, 16));
      tm = fmaxf(tm, __shfl_xor(tm, 32));
      float mn = fmaxf(mrow, tm);
      float fac = __expf(mrow - mn);
      mrow = mn;
      float rs = 0.f;
      #pragma unroll
      for (int nt = 0; nt < 4; ++nt) {
        #pragma unroll
        for (int i = 0; i < 4; ++i) {
          float pv = __expf(s[nt][i] - mn);
          s[nt][i] = pv;
          rs += pv;
        }
      }
      rs += __shfl_xor(rs, 16);
      rs += __shfl_xor(rs, 32);
      lrow = lrow * fac + rs;
      #pragma unroll
      for (int nt2 = 0; nt2 < 8; ++nt2) {
        #pragma unroll
        for (int i = 0; i < 4; ++i) o[nt2][i] *= fac;
      }
      unsigned pk0[4], pk1[4];
      #pragma unroll
      for (int nt = 0; nt < 4; ++nt) {
        pk0[nt] = pack2bf(s[nt][0], s[nt][1]);
        pk1[nt] = pack2bf(s[nt][2], s[nt][3]);
      }
      const int srcA = lm + ((lg & 1) << 5);
      const int srcB = srcA + 16;
      const bool lo2 = (lg < 2);
      bf16x8 pb[2];
      #pragma unroll
      for (int kc = 0; kc < 2; ++kc) {
        int a0 = __shfl((int)pk0[2*kc], srcA), b0 = __shfl((int)pk0[2*kc+1], srcA);
        int a1 = __shfl((int)pk1[2*kc], srcA), b1 = __shfl((int)pk1[2*kc+1], srcA);
        int a2 = __shfl((int)pk0[2*kc], srcB), b2 = __shfl((int)pk0[2*kc+1], srcB);
        int a3 = __shfl((int)pk1[2*kc], srcB), b3 = __shfl((int)pk1[2*kc+1], srcB);
        union { int uu[4]; bf16x8 v; } pw;
        pw.uu[0] = lo2 ? a0 : b0;
        pw.uu[1] = lo2 ? a1 : b1;
        pw.uu[2] = lo2 ? a2 : b2;
        pw.uu[3] = lo2 ? a3 : b3;
        pb[kc] = pw.v;
      }
      #pragma unroll
      for (int nt2 = 0; nt2 < 8; ++nt2) {
        int dr = (nt2 << 4) + lm;
        #pragma unroll
        for (int kc = 0; kc < 2; ++kc) {
          int byte = (dr << 7) + (((kc << 6) + (lg << 4)) ^ ((dr & 7) << 4));
          bf16x8 vb = *(const bf16x8*)(Vlds + byte);
          o[nt2] = __builtin_amdgcn_mfma_f32_16x16x32_bf16(vb, pb[kc], o[nt2], 0, 0, 0);
        }
      }
    }
    if (have_next) {
      WRITELDS(smem + ((cur ^ 1) << 15));
    }
    __syncthreads();
    cur ^= 1;
  }
  float inv = 1.f / lrow;
  float* orow = out + (size_t)myrow * ODIM + h * HD + (lg << 2);
  #pragma unroll
  for (int nt2 = 0; nt2 < 8; ++nt2) {
    float4 st = {o[nt2][0] * inv, o[nt2][1] * inv, o[nt2][2] * inv, o[nt2][3] * inv};
    *(float4*)(orow + (nt2 << 4)) = st;
  }
#undef LOADT
#undef WRITELDS
}

extern "C" void kernel_launch(void* const* d_in, const int* in_sizes, int n_in,
                              void* d_out, int out_size, void* d_ws, size_t ws_size,
                              hipStream_t stream) {
  const float* q = (const float*)d_in[1];
  const float* k = (const float*)d_in[2];
  const float* v = (const float*)d_in[3];
  float* out = (float*)d_out;
  dim3 grid(SEQ / QB / 2, NH);  // 16 balanced Q-tile pairs x 32 heads
  const size_t need = (size_t)(NKV * 32 * 16384) * 2;  // 8 MB K+V images
  if (ws_size >= need && d_ws != nullptr) {
    unsigned char* ws = (unsigned char*)d_ws;
    int total = KWORK + VWORK;
    sdpa_prepass<<<(total + 255) / 256, 256, 0, stream>>>(k, v, ws);
    sdpa_flash_kernel<<<grid, 512, 0, stream>>>(
        q, ws, ws + (NKV * 32 * 16384), out);
  } else {
    sdpa_flash_fb<<<grid, 512, 0, stream>>>(q, k, v, out);
  }
}